// Round 2
// baseline (880.921 us; speedup 1.0000x reference)
//
#include <hip/hip_runtime.h>

#define D 768
#define D3 2304

typedef __bf16 bf16x8 __attribute__((ext_vector_type(8)));
typedef float f32x4 __attribute__((ext_vector_type(4)));

__device__ __forceinline__ float b2f(unsigned short u) {
    unsigned int i = ((unsigned int)u) << 16;
    return __builtin_bit_cast(float, i);
}
__device__ __forceinline__ unsigned short f2b(float f) {
    unsigned int i = __builtin_bit_cast(unsigned int, f);
    i += 0x7FFFu + ((i >> 16) & 1u);   // RNE
    return (unsigned short)(i >> 16);
}
__device__ __forceinline__ float sigm(float x) { return 1.0f / (1.0f + __expf(-x)); }

// fp32 -> bf16 cast, 4 elems/thread (all our tensors are multiples of 4)
__global__ void k_cast(const float* __restrict__ in, unsigned short* __restrict__ out, int n)
{
    int i4 = (blockIdx.x * blockDim.x + threadIdx.x) * 4;
    if (i4 >= n) return;
    float4 v = *(const float4*)(in + i4);
    ushort4 u;
    u.x = f2b(v.x); u.y = f2b(v.y); u.z = f2b(v.z); u.w = f2b(v.w);
    *(ushort4*)(out + i4) = u;
}

// ---------------------------------------------------------------------------
// NT GEMM: C[M,N] = act(A[M,K] @ B[N,K]^T + bias[N])
// A,B bf16 (row-major, K contiguous). bias fp32. OBF: store bf16 else f32.
// 64x64 tile, BK=32, 4 waves; wave w does rows [16w,16w+16), all 64 cols.
// MFMA 16x16x32 bf16; layouts per verified m89/m92.
// ---------------------------------------------------------------------------
template<int ACT, bool OBF>
__global__ __launch_bounds__(256)
void gemm_nt(const unsigned short* __restrict__ A,
             const unsigned short* __restrict__ B,
             const float* __restrict__ bias,
             void* __restrict__ Cv,
             int M, int N, int K)
{
    constexpr int BM = 64, BN = 64, BK = 32;
    __shared__ __align__(16) unsigned short As[BM * BK];
    __shared__ __align__(16) unsigned short Bs[BN * BK];

    const int bm   = blockIdx.y * BM;
    const int bn   = blockIdx.x * BN;
    const int tid  = threadIdx.x;
    const int wave = tid >> 6;
    const int lane = tid & 63;

    const int srow = tid >> 2;
    const int scol = (tid & 3) << 3;

    int arow = bm + srow; if (arow >= M) arow = M - 1;
    int brow = bn + srow; if (brow >= N) brow = N - 1;
    const unsigned short* Ap = A + (size_t)arow * K + scol;
    const unsigned short* Bp = B + (size_t)brow * K + scol;
    unsigned short* AsP = &As[srow * BK + scol];
    unsigned short* BsP = &Bs[srow * BK + scol];

    const int fr = lane & 15;
    const int fk = (lane >> 4) << 3;

    f32x4 acc[4];
#pragma unroll
    for (int i = 0; i < 4; ++i) acc[i] = (f32x4)0.0f;

    for (int k0 = 0; k0 < K; k0 += BK) {
        *(uint4*)AsP = *(const uint4*)(Ap + k0);
        *(uint4*)BsP = *(const uint4*)(Bp + k0);
        __syncthreads();
        bf16x8 a = *(const bf16x8*)&As[(wave * 16 + fr) * BK + fk];
#pragma unroll
        for (int ct = 0; ct < 4; ++ct) {
            bf16x8 b = *(const bf16x8*)&Bs[(ct * 16 + fr) * BK + fk];
            acc[ct] = __builtin_amdgcn_mfma_f32_16x16x32_bf16(a, b, acc[ct], 0, 0, 0);
        }
        __syncthreads();
    }

    const int rbase = bm + wave * 16 + ((lane >> 4) << 2);
#pragma unroll
    for (int ct = 0; ct < 4; ++ct) {
        int col = bn + ct * 16 + (lane & 15);
        if (col >= N) continue;
        float bv = bias ? bias[col] : 0.0f;
#pragma unroll
        for (int r = 0; r < 4; ++r) {
            int row = rbase + r;
            if (row < M) {
                float v = acc[ct][r] + bv;
                if (ACT == 1) v = tanhf(v);
                if (OBF) ((unsigned short*)Cv)[(size_t)row * N + col] = f2b(v);
                else     ((float*)Cv)[(size_t)row * N + col] = v;
            }
        }
    }
}

// gi0[j] = dot(enc, W_ih[j,:]) + b_ih[j]  (all fp32). One wave per output j.
__global__ void k_gi0(const float* __restrict__ enc,
                      const float* __restrict__ Wih,
                      const float* __restrict__ bih,
                      float* __restrict__ gi0)
{
    int j = blockIdx.x * 4 + (threadIdx.x >> 6);
    int lane = threadIdx.x & 63;
    if (j >= D3) return;
    const float* w = Wih + (size_t)j * D;
    float s = 0.0f;
    for (int k = lane; k < D; k += 64) s += enc[k] * w[k];
#pragma unroll
    for (int off = 32; off > 0; off >>= 1) s += __shfl_xor(s, off, 64);
    if (lane == 0) gi0[j] = s + bih[j];
}

// r0 = GRU(x=enc via gi0 row, h=sub) using gh = sub@Whh^T+bhh. r0 out bf16.
__global__ void k_r0(const float* __restrict__ gi0, const float* __restrict__ gh,
                     const unsigned short* __restrict__ sub,
                     unsigned short* __restrict__ r0, int S)
{
    int idx = blockIdx.x * blockDim.x + threadIdx.x;
    if (idx >= S * D) return;
    int s = idx / D, d = idx - s * D;
    const float* g = gh + (size_t)s * D3;
    float r = sigm(gi0[d] + g[d]);
    float z = sigm(gi0[D + d] + g[D + d]);
    float n = tanhf(gi0[2 * D + d] + r * g[2 * D + d]);
    float h = b2f(sub[idx]);
    r0[idx] = f2b((1.0f - z) * n + z * h);
}

// rj[e,:] = GRU(x=r0[head] via Gi rows, h=rel[type] via Ghr rows). rj out bf16.
__global__ void k_edge(const int* __restrict__ heads, const int* __restrict__ types,
                       const float* __restrict__ Gi, const float* __restrict__ Ghr,
                       const float* __restrict__ rel,
                       unsigned short* __restrict__ rj, int E)
{
    int idx = blockIdx.x * blockDim.x + threadIdx.x;
    if (idx >= E * D) return;
    int e = idx / D, d = idx - e * D;
    int hd = heads[e], t = types[e];
    const float* gi = Gi + (size_t)hd * D3;
    const float* gh = Ghr + (size_t)t * D3;
    float r = sigm(gi[d] + gh[d]);
    float z = sigm(gi[D + d] + gh[D + d]);
    float n = tanhf(gi[2 * D + d] + r * gh[2 * D + d]);
    float h = rel[(size_t)t * D + d];
    rj[idx] = f2b((1.0f - z) * n + z * h);
}

__global__ void k_seed_st(const int* __restrict__ se, int* __restrict__ seed_pos,
                          int* __restrict__ best, int S, int stride)
{
    int s = blockIdx.x * blockDim.x + threadIdx.x;
    if (s >= S) return;
    int node = se[s];
    atomicMax(&seed_pos[node], s);
    atomicMax(&best[node], s * stride);
}

__global__ void k_edge_time(const int* __restrict__ heads, const int* __restrict__ tails,
                            const int* __restrict__ seed_pos, int* __restrict__ best,
                            int E, int stride)
{
    int e = blockIdx.x * blockDim.x + threadIdx.x;
    if (e >= E) return;
    int p = seed_pos[heads[e]];
    int t = p * stride + 1 + e;
    if (t < 0) return;
    atomicMax(&best[tails[e]], t);
}

__global__ void k_seed_win(const int* __restrict__ se, const int* __restrict__ best,
                           int* __restrict__ winner, int S, int stride)
{
    int s = blockIdx.x * blockDim.x + threadIdx.x;
    if (s >= S) return;
    int node = se[s];
    if (best[node] == s * stride) winner[node] = s;
}

__global__ void k_edge_win(const int* __restrict__ heads, const int* __restrict__ tails,
                           const int* __restrict__ seed_pos, const int* __restrict__ best,
                           int* __restrict__ winner, int E, int S, int stride)
{
    int e = blockIdx.x * blockDim.x + threadIdx.x;
    if (e >= E) return;
    int p = seed_pos[heads[e]];
    int t = p * stride + 1 + e;
    if (t < 0) return;
    int node = tails[e];
    if (best[node] == t) winner[node] = S + e;
}

// out[i,:] (fp32) = written ? (winner<S ? sub[winner] : obj[winner-S]) : default[i]
__global__ void k_out(const int* __restrict__ n2n, const int* __restrict__ oldnd,
                      const int* __restrict__ best, const int* __restrict__ winner,
                      const unsigned short* __restrict__ sub,
                      const unsigned short* __restrict__ obj,
                      const float* __restrict__ defnd,
                      float* __restrict__ out, int N, int S)
{
    int idx = blockIdx.x * blockDim.x + threadIdx.x;
    const int JP = D / 4;
    if (idx >= N * JP) return;
    int i = idx / JP, j = idx - i * JP;
    int id = n2n[oldnd[i]];
    float4 v;
    if (best[id] >= 0) {
        int w = winner[id];
        const unsigned short* src = (w < S) ? sub + (size_t)w * D + j * 4
                                            : obj + (size_t)(w - S) * D + j * 4;
        ushort4 u = *(const ushort4*)src;
        v.x = b2f(u.x); v.y = b2f(u.y); v.z = b2f(u.z); v.w = b2f(u.w);
    } else {
        v = *(const float4*)(defnd + (size_t)i * D + j * 4);
    }
    *(float4*)(out + (size_t)i * D + j * 4) = v;
}

extern "C" void kernel_launch(void* const* d_in, const int* in_sizes, int n_in,
                              void* d_out, int out_size, void* d_ws, size_t ws_size,
                              hipStream_t stream)
{
    const float* enc    = (const float*)d_in[0];
    const float* smask  = (const float*)d_in[1];
    const int* seed_ent = (const int*)d_in[2];
    const int* eheads   = (const int*)d_in[3];
    const int* etails   = (const int*)d_in[4];
    const int* etype    = (const int*)d_in[5];
    const int* n2n      = (const int*)d_in[6];
    const int* oldnd    = (const int*)d_in[7];
    const float* rel    = (const float*)d_in[8];
    const float* Wsub   = (const float*)d_in[9];
    const float* bsub   = (const float*)d_in[10];
    const float* Wobj   = (const float*)d_in[11];
    const float* bobj   = (const float*)d_in[12];
    const float* Wih    = (const float*)d_in[13];
    const float* Whh    = (const float*)d_in[14];
    const float* bih    = (const float*)d_in[15];
    const float* bhh    = (const float*)d_in[16];
    const float* defnd  = (const float*)d_in[17];

    const int S = in_sizes[2];
    const int E = in_sizes[3];
    const int N = in_sizes[6];
    const int R = in_sizes[8] / D;
    const int stride = E + 1;

    // workspace carve (256B aligned), ~150 MB total
    char* p = (char*)d_ws;
    auto carve = [&](size_t bytes) -> char* {
        char* r = p; p += (bytes + 255) & ~(size_t)255; return r;
    };
    unsigned short* smask_b = (unsigned short*)carve((size_t)S * D * 2);
    unsigned short* Wsub_b  = (unsigned short*)carve((size_t)D * D * 2);
    unsigned short* Wobj_b  = (unsigned short*)carve((size_t)D * D * 2);
    unsigned short* Wih_b   = (unsigned short*)carve((size_t)D3 * D * 2);
    unsigned short* Whh_b   = (unsigned short*)carve((size_t)D3 * D * 2);
    unsigned short* rel_b   = (unsigned short*)carve((size_t)R * D * 2);
    unsigned short* sub     = (unsigned short*)carve((size_t)S * D * 2);
    unsigned short* r0      = (unsigned short*)carve((size_t)S * D * 2);
    unsigned short* rj      = (unsigned short*)carve((size_t)E * D * 2);
    unsigned short* obj     = (unsigned short*)carve((size_t)E * D * 2);
    float* gi0 = (float*)carve((size_t)D3 * 4);
    float* gh  = (float*)carve((size_t)S * D3 * 4);   // reused as Gi
    float* ghr = (float*)carve((size_t)R * D3 * 4);
    int* seed_pos = (int*)carve((size_t)N * 4);
    int* best     = (int*)carve((size_t)N * 4);
    int* winner   = (int*)carve((size_t)N * 4);

    dim3 blk(256);
    auto g1 = [](int n) { return dim3((n + 255) / 256); };

    hipMemsetAsync(seed_pos, 0xFF, (size_t)N * 4, stream);
    hipMemsetAsync(best,     0xFF, (size_t)N * 4, stream);
    hipMemsetAsync(winner,   0xFF, (size_t)N * 4, stream);

    // fp32 -> bf16 casts for GEMM operands
    k_cast<<<g1(S * D / 4),  blk, 0, stream>>>(smask, smask_b, S * D);
    k_cast<<<g1(D * D / 4),  blk, 0, stream>>>(Wsub,  Wsub_b,  D * D);
    k_cast<<<g1(D * D / 4),  blk, 0, stream>>>(Wobj,  Wobj_b,  D * D);
    k_cast<<<g1(D3 * D / 4), blk, 0, stream>>>(Wih,   Wih_b,   D3 * D);
    k_cast<<<g1(D3 * D / 4), blk, 0, stream>>>(Whh,   Whh_b,   D3 * D);
    k_cast<<<g1(R * D / 4),  blk, 0, stream>>>(rel,   rel_b,   R * D);

    // sub = tanh(smask @ Wsub^T + bsub)  [S,D] bf16
    gemm_nt<1, true><<<dim3(D / 64, (S + 63) / 64), blk, 0, stream>>>(
        smask_b, Wsub_b, bsub, sub, S, D, D);
    // gi0 row (fp32 exact)
    k_gi0<<<dim3((D3 + 3) / 4), blk, 0, stream>>>(enc, Wih, bih, gi0);
    // gh = sub @ Whh^T + bhh  [S,3D] f32
    gemm_nt<0, false><<<dim3(D3 / 64, (S + 63) / 64), blk, 0, stream>>>(
        sub, Whh_b, bhh, gh, S, D3, D);
    // r0 combine -> bf16
    k_r0<<<g1(S * D), blk, 0, stream>>>(gi0, gh, sub, r0, S);
    // Gi = r0 @ Wih^T + bih  [S,3D] f32 (reuse gh buffer)
    gemm_nt<0, false><<<dim3(D3 / 64, (S + 63) / 64), blk, 0, stream>>>(
        r0, Wih_b, bih, gh, S, D3, D);
    // Ghr = rel @ Whh^T + bhh  [R,3D] f32
    gemm_nt<0, false><<<dim3(D3 / 64, (R + 63) / 64), blk, 0, stream>>>(
        rel_b, Whh_b, bhh, ghr, R, D3, D);
    // rj per edge -> bf16
    k_edge<<<g1(E * D), blk, 0, stream>>>(eheads, etype, gh, ghr, rel, rj, E);
    // obj = tanh(rj @ Wobj^T + bobj)  [E,D] bf16
    gemm_nt<1, true><<<dim3(D / 64, (E + 63) / 64), blk, 0, stream>>>(
        rj, Wobj_b, bobj, obj, E, D, D);

    // timestamps / winners
    k_seed_st<<<g1(S), blk, 0, stream>>>(seed_ent, seed_pos, best, S, stride);
    k_edge_time<<<g1(E), blk, 0, stream>>>(eheads, etails, seed_pos, best, E, stride);
    k_seed_win<<<g1(S), blk, 0, stream>>>(seed_ent, best, winner, S, stride);
    k_edge_win<<<g1(E), blk, 0, stream>>>(eheads, etails, seed_pos, best, winner, E, S, stride);

    // output (fp32)
    k_out<<<g1(N * (D / 4)), blk, 0, stream>>>(
        n2n, oldnd, best, winner, sub, obj, defnd, (float*)d_out, N, S);
}